// Round 1
// baseline (174.620 us; speedup 1.0000x reference)
//
#include <hip/hip_runtime.h>
#include <hip/hip_bf16.h>

#define B_    4
#define N_    16384
#define D_    128
#define P_    100
#define BN_   65536      // B_*N_
#define PBN_  6553600    // P_*BN_
#define PPAD  112        // P padded to 7*16 MFMA p-tiles (k_proj)
#define KPAD  128        // P padded to 128 for k_comb's K dimension
#define NBIN  4096

typedef __attribute__((ext_vector_type(8))) short short8;   // 8 bf16 = 4 VGPR
typedef __attribute__((ext_vector_type(4))) float floatx4;  // MFMA C/D

// bf16 <-> f32 via raw bits (RNE; inputs are finite)
__device__ __forceinline__ unsigned short f2b(float f) {
    unsigned u = __float_as_uint(f);
    return (unsigned short)((u + 0x7FFFu + ((u >> 16) & 1u)) >> 16);
}
__device__ __forceinline__ float b2f(unsigned short h) {
    return __uint_as_float(((unsigned)h) << 16);
}

// ---------------------------------------------------------------------------
// Kernel 1: theta normalization -> thb[p][d] (for k_proj, rows >=100 zero)
// and thbT[d][p] (for k_comb B-operand, cols >=100 zero; true zeros so the
// MFMA K-pad is NaN-safe).
// ---------------------------------------------------------------------------
__global__ void k_norm(const float* __restrict__ th,
                       unsigned short* __restrict__ thb,
                       unsigned short* __restrict__ thbT) {
    int p = blockIdx.x;       // 0..127
    int d = threadIdx.x;      // 0..127
    float v = 0.f;
    if (p < P_) v = th[p * D_ + d];
    float s = v * v;
    #pragma unroll
    for (int o = 32; o > 0; o >>= 1) s += __shfl_down(s, o, 64);
    __shared__ float red[2];
    if ((d & 63) == 0) red[d >> 6] = s;
    __syncthreads();
    float norm = fmaxf(sqrtf(red[0] + red[1]), 1e-12f);
    unsigned short r = f2b(v / norm);       // p>=100 -> 0/1e-12 = +0
    if (p < PPAD) thb[p * D_ + d] = r;
    thbT[d * KPAD + p] = r;
}

// ---------------------------------------------------------------------------
// Kernel 2: projections via bf16 MFMA 16x16x32 (unchanged — proven).
// ---------------------------------------------------------------------------
__global__ __launch_bounds__(256) void k_proj(
    const float* __restrict__ x, const float* __restrict__ y,
    const unsigned short* __restrict__ thb,
    unsigned short* __restrict__ xp, unsigned short* __restrict__ yp) {
    __shared__ unsigned short smem[32640];    // 65,280 B
    unsigned short* th_s = smem;              // [112][136]
    unsigned short* xs   = smem + 15232;      // [64][136]
    unsigned short* ys   = xs + 8704;         // [64][136]
    unsigned short* bufx = xs;                // [112][72] (alias, phase 2)
    unsigned short* bufy = bufx + 8064;       // [112][72]
    const int tid  = threadIdx.x;
    const int w    = tid >> 6;                // wave 0..3 -> rows w*16..+15
    const int lane = tid & 63;
    const int n    = lane & 15;
    const int quad = lane >> 4;
    const int row0 = blockIdx.x * 64;

    for (int g = tid; g < 1792; g += 256) {   // theta 112x128 bf16
        int r = g >> 4, c = (g & 15) << 3;
        *(uint4*)(th_s + r * 136 + c) = *(const uint4*)(thb + r * D_ + c);
    }
    for (int g = tid; g < 2048; g += 256) {   // x,y 64x128 fp32 -> bf16
        int r = g >> 5, c = (g & 31) << 2;
        float4 vx = *(const float4*)(x + (size_t)(row0 + r) * D_ + c);
        float4 vy = *(const float4*)(y + (size_t)(row0 + r) * D_ + c);
        *(ushort4*)(xs + r * 136 + c) =
            make_ushort4(f2b(vx.x), f2b(vx.y), f2b(vx.z), f2b(vx.w));
        *(ushort4*)(ys + r * 136 + c) =
            make_ushort4(f2b(vy.x), f2b(vy.y), f2b(vy.z), f2b(vy.w));
    }
    __syncthreads();

    short8 bx[4], by[4];
    #pragma unroll
    for (int ks = 0; ks < 4; ++ks) {
        bx[ks] = *(const short8*)(xs + (w * 16 + n) * 136 + ks * 32 + quad * 8);
        by[ks] = *(const short8*)(ys + (w * 16 + n) * 136 + ks * 32 + quad * 8);
    }
    __syncthreads();                          // xs/ys dead -> buf aliases ok

    #pragma unroll
    for (int pt = 0; pt < 7; ++pt) {
        floatx4 accx = {0.f, 0.f, 0.f, 0.f};
        floatx4 accy = {0.f, 0.f, 0.f, 0.f};
        #pragma unroll
        for (int ks = 0; ks < 4; ++ks) {
            short8 a = *(const short8*)(th_s + (pt * 16 + n) * 136 + ks * 32 + quad * 8);
            accx = __builtin_amdgcn_mfma_f32_16x16x32_bf16(a, bx[ks], accx, 0, 0, 0);
            accy = __builtin_amdgcn_mfma_f32_16x16x32_bf16(a, by[ks], accy, 0, 0, 0);
        }
        #pragma unroll
        for (int reg = 0; reg < 4; ++reg) {
            int p = pt * 16 + quad * 4 + reg;
            bufx[p * 72 + w * 16 + n] = f2b(accx[reg]);
            bufy[p * 72 + w * 16 + n] = f2b(accy[reg]);
        }
    }
    __syncthreads();

    for (int g = tid; g < 896; g += 256) {
        int p = g >> 3, c = (g & 7) << 3;
        *(uint4*)(xp + (size_t)p * BN_ + row0 + c) = *(const uint4*)(bufx + p * 72 + c);
        *(uint4*)(yp + (size_t)p * BN_ + row0 + c) = *(const uint4*)(bufy + p * 72 + c);
    }
}

// ---------------------------------------------------------------------------
// Kernel 3: fused counting sort + rank + diff.  NEW: x and y counts share one
// packed histogram (y = low 16 bits via +1, x = high 16 bits via +0x10000;
// max count 16384 < 2^16 so fields never interact, and the packed exclusive
// scan is field-independent too: total = 0x4000_4000, no carry).  This
// collapses the former two count->scan->barrier pipelines into ONE: saves a
// 4096-entry hist zero, a full scan4 (6 shfl levels + serial-16 + 8K LDS
// words), and ~4 of 11 block-wide barriers — the critical path of a 16-wave
// block.  Atomic op count unchanged.  uint4 global I/O.
// ---------------------------------------------------------------------------
__device__ __forceinline__ int binof(float v) {
    int k = (int)((v + 8.0f) * 256.0f);
    return k < 0 ? 0 : (k > NBIN - 1 ? NBIN - 1 : k);
}

__device__ __forceinline__ void scan4(unsigned* hist, volatile unsigned* wsum, int t) {
    unsigned v[4], run = 0;
    #pragma unroll
    for (int i = 0; i < 4; ++i) { unsigned h = hist[t * 4 + i]; v[i] = run; run += h; }
    const int lane = t & 63, w = t >> 6;
    unsigned inc = run;
    #pragma unroll
    for (int off = 1; off < 64; off <<= 1) {
        unsigned nbr = __shfl_up(inc, off, 64);
        if (lane >= off) inc += nbr;
    }
    if (lane == 63) wsum[w] = inc;
    __syncthreads();
    if (t == 0) {
        unsigned r2 = 0;
        #pragma unroll
        for (int i = 0; i < 16; ++i) { unsigned h = wsum[i]; wsum[i] = r2; r2 += h; }
    }
    __syncthreads();
    unsigned base = wsum[w] + (inc - run);
    #pragma unroll
    for (int i = 0; i < 4; ++i) hist[t * 4 + i] = base + v[i];
}

__global__ __launch_bounds__(1024, 8) void k_sortdiff(
    const unsigned short* __restrict__ xp, const unsigned short* __restrict__ yp,
    unsigned short* __restrict__ diff) {
    __shared__ unsigned hist[NBIN];           // 16 KB (packed y|x)
    __shared__ unsigned short ysort[N_];      // 32 KB
    __shared__ unsigned wsum[16];
    const size_t base = (size_t)blockIdx.x * N_ + (size_t)threadIdx.x * 16;
    const int t = threadIdx.x;

    // 16 contiguous elements per thread, uint4 loads (coalesced 2KB/wave)
    unsigned yw[8], xw[8];
    {
        uint4 a = *(const uint4*)(yp + base), b = *(const uint4*)(yp + base + 8);
        yw[0]=a.x; yw[1]=a.y; yw[2]=a.z; yw[3]=a.w;
        yw[4]=b.x; yw[5]=b.y; yw[6]=b.z; yw[7]=b.w;
        uint4 c = *(const uint4*)(xp + base), d = *(const uint4*)(xp + base + 8);
        xw[0]=c.x; xw[1]=c.y; xw[2]=c.z; xw[3]=c.w;
        xw[4]=d.x; xw[5]=d.y; xw[6]=d.z; xw[7]=d.w;
    }

    #pragma unroll
    for (int i = 0; i < 4; ++i) hist[t + i * 1024] = 0;
    __syncthreads();

    // ---- single packed count pass (returning: ret field IS intra-bin idx) ----
    unsigned jy[8], jx[8];
    #pragma unroll
    for (int k = 0; k < 8; ++k) {
        unsigned j0 = atomicAdd(&hist[binof(b2f((unsigned short)(yw[k] & 0xffff)))], 1u);
        unsigned j1 = atomicAdd(&hist[binof(b2f((unsigned short)(yw[k] >> 16)))], 1u);
        jy[k] = (j0 & 0xffffu) | (j1 << 16);
        unsigned i0 = atomicAdd(&hist[binof(b2f((unsigned short)(xw[k] & 0xffff)))], 0x10000u);
        unsigned i1 = atomicAdd(&hist[binof(b2f((unsigned short)(xw[k] >> 16)))], 0x10000u);
        jx[k] = (i0 >> 16) | (i1 & 0xffff0000u);
    }
    __syncthreads();
    scan4(hist, wsum, t);                     // packed exclusive prefix, both fields
    __syncthreads();

    // scatter y into LDS (low field) and fold x rank into jx (high field)
    #pragma unroll
    for (int k = 0; k < 8; ++k) {
        unsigned short e0 = (unsigned short)(yw[k] & 0xffff);
        unsigned short e1 = (unsigned short)(yw[k] >> 16);
        ysort[(hist[binof(b2f(e0))] & 0xffffu) + (jy[k] & 0xffffu)] = e0;
        ysort[(hist[binof(b2f(e1))] & 0xffffu) + (jy[k] >> 16)]     = e1;
        unsigned r0 = (hist[binof(b2f((unsigned short)(xw[k] & 0xffff)))] >> 16) + (jx[k] & 0xffffu);
        unsigned r1 = (hist[binof(b2f((unsigned short)(xw[k] >> 16)))] >> 16) + (jx[k] >> 16);
        jx[k] = r0 | (r1 << 16);
    }
    __syncthreads();

    // gather transported y, write diff
    unsigned ow[8];
    #pragma unroll
    for (int k = 0; k < 8; ++k) {
        float x0 = b2f((unsigned short)(xw[k] & 0xffff));
        float x1 = b2f((unsigned short)(xw[k] >> 16));
        unsigned short d0 = f2b(b2f(ysort[jx[k] & 0xffffu]) - x0);
        unsigned short d1 = f2b(b2f(ysort[jx[k] >> 16]) - x1);
        ow[k] = (unsigned)d0 | ((unsigned)d1 << 16);
    }
    *(uint4*)(diff + base)     = make_uint4(ow[0], ow[1], ow[2], ow[3]);
    *(uint4*)(diff + base + 8) = make_uint4(ow[4], ow[5], ow[6], ow[7]);
}

// ---------------------------------------------------------------------------
// Kernel 4: combine via bf16 MFMA, with the former k_trans transpose FUSED
// into the LDS stage (kills 16.8 MB diffT write + 16.8 MB read + a launch).
// Per block: stage diff[p][row0..row0+64] for p=0..99 (100 coalesced 128 B
// segments — identical pattern k_trans used) pair-packed into Lp[k2][row]
// (dword = {k even lo16, k odd hi16}); k2 rows 50..63 zeroed = NaN-safe
// K-pad.  A-frags: 4x ds_read_b32 per ks at (k2)*68 + r dwords — lanes map
// to bank (16*quad + n16) mod 32 = exact 2-way aliasing = free (m136).
// B = thbT staged in LDS [128][136] (proven).  C[m=row][n=d]; out = x + C/P.
// LDS 52,224 B -> 3 blocks/CU, 12 waves/CU (HBM-bound, sufficient).
// ---------------------------------------------------------------------------
__global__ __launch_bounds__(256) void k_comb(
    const float* __restrict__ x, const unsigned short* __restrict__ diff,
    const unsigned short* __restrict__ thbT, float* __restrict__ out) {
    __shared__ unsigned short ths[128 * 136]; // 34,816 B
    __shared__ unsigned Lp[64 * 68];          // 17,408 B  [k2][row] pair-packed
    const int tid  = threadIdx.x;
    const int w    = tid >> 6;                // wave -> rows w*16..+15
    const int lane = tid & 63;
    const int n16  = lane & 15;
    const int quad = lane >> 4;
    const int row0 = blockIdx.x * 64;

    for (int g = tid; g < 2048; g += 256) {   // thbT 128x128 bf16 -> LDS
        int r = g >> 4, c = (g & 15) << 3;
        *(uint4*)(ths + r * 136 + c) = *(const uint4*)(thbT + r * KPAD + c);
    }
    for (int g = tid; g < 952; g += 256) Lp[50 * 68 + g] = 0;   // k2=50..63 pad
    for (int g = tid; g < 400; g += 256) {    // 50 p-pairs x 8 row-groups
        int p2 = g >> 3, rg = (g & 7) << 3;
        uint4 a = *(const uint4*)(diff + (size_t)(2 * p2) * BN_ + row0 + rg);
        uint4 b = *(const uint4*)(diff + (size_t)(2 * p2 + 1) * BN_ + row0 + rg);
        unsigned* dst = Lp + p2 * 68 + rg;
        dst[0] = (a.x & 0xffffu) | (b.x << 16);
        dst[1] = (a.x >> 16)     | (b.x & 0xffff0000u);
        dst[2] = (a.y & 0xffffu) | (b.y << 16);
        dst[3] = (a.y >> 16)     | (b.y & 0xffff0000u);
        dst[4] = (a.z & 0xffffu) | (b.z << 16);
        dst[5] = (a.z >> 16)     | (b.z & 0xffff0000u);
        dst[6] = (a.w & 0xffffu) | (b.w << 16);
        dst[7] = (a.w >> 16)     | (b.w & 0xffff0000u);
    }
    __syncthreads();

    // A-frags: lane row r = w*16+n16, k = ks*32 + quad*8 + 0..7
    const int r = w * 16 + n16;
    short8 af[4];
    #pragma unroll
    for (int ks = 0; ks < 4; ++ks) {
        union { unsigned u[4]; short8 v; } tu;
        #pragma unroll
        for (int m = 0; m < 4; ++m)
            tu.u[m] = Lp[(ks * 16 + quad * 4 + m) * 68 + r];
        af[ks] = tu.v;
    }

    floatx4 acc[8];
    #pragma unroll
    for (int nt = 0; nt < 8; ++nt) {
        acc[nt] = (floatx4){0.f, 0.f, 0.f, 0.f};
        #pragma unroll
        for (int ks = 0; ks < 4; ++ks) {
            short8 b = *(const short8*)(ths + (nt * 16 + n16) * 136 + ks * 32 + quad * 8);
            acc[nt] = __builtin_amdgcn_mfma_f32_16x16x32_bf16(af[ks], b, acc[nt], 0, 0, 0);
        }
    }

    const float invP = 1.0f / (float)P_;
    const size_t rbase = (size_t)(row0 + w * 16 + quad * 4) * D_ + n16;
    #pragma unroll
    for (int nt = 0; nt < 8; ++nt)
        #pragma unroll
        for (int reg = 0; reg < 4; ++reg) {
            size_t o = rbase + (size_t)reg * D_ + nt * 16;
            out[o] = fmaf(acc[nt][reg], invP, x[o]);
        }
}

// ---------------------------------------------------------------------------
// Workspace (bytes): thb[0, 32KB) thbT[32KB, 64KB) xp[64KB, +13.1MB)
// yp(+13.1MB) => ~26.3 MB. diff overwrites xp in place.
// ---------------------------------------------------------------------------
extern "C" void kernel_launch(void* const* d_in, const int* in_sizes, int n_in,
                              void* d_out, int out_size, void* d_ws, size_t ws_size,
                              hipStream_t stream) {
    const float* x  = (const float*)d_in[0];
    const float* y  = (const float*)d_in[1];
    const float* th = (const float*)d_in[2];
    float* out = (float*)d_out;
    char*  wsb = (char*)d_ws;

    unsigned short* thb  = (unsigned short*)wsb;
    unsigned short* thbT = (unsigned short*)(wsb + 32768);
    unsigned short* xpb  = (unsigned short*)(wsb + 65536);
    unsigned short* ypb  = xpb + PBN_;

    k_norm<<<128, 128, 0, stream>>>(th, thb, thbT);
    k_proj<<<BN_ / 64, 256, 0, stream>>>(x, y, thb, xpb, ypb);
    k_sortdiff<<<P_ * B_, 1024, 0, stream>>>(xpb, ypb, xpb);
    k_comb<<<BN_ / 64, 256, 0, stream>>>(x, xpb, thbT, out);
}

// Round 2
// 154.352 us; speedup vs baseline: 1.1313x; 1.1313x over previous
//
#include <hip/hip_runtime.h>
#include <hip/hip_bf16.h>

#define B_    4
#define N_    16384
#define D_    128
#define P_    100
#define BN_   65536      // B_*N_
#define PBN_  6553600    // P_*BN_
#define PPAD  112        // P padded to 7*16 MFMA p-tiles (k_proj)
#define KPAD  128        // P padded to 128 for k_comb's K dimension
#define NBIN  4096

typedef __attribute__((ext_vector_type(8))) short short8;   // 8 bf16 = 4 VGPR
typedef __attribute__((ext_vector_type(4))) float floatx4;  // MFMA C/D

// bf16 <-> f32 via raw bits (RNE; inputs are finite)
__device__ __forceinline__ unsigned short f2b(float f) {
    unsigned u = __float_as_uint(f);
    return (unsigned short)((u + 0x7FFFu + ((u >> 16) & 1u)) >> 16);
}
__device__ __forceinline__ float b2f(unsigned short h) {
    return __uint_as_float(((unsigned)h) << 16);
}

// ---------------------------------------------------------------------------
// Kernel 1: theta normalization -> thb[p][d] (for k_proj, rows >=100 zero)
// and thbT[d][p] (for k_comb B-operand, cols >=100 zero; true zeros so the
// MFMA K-pad is NaN-safe).
// ---------------------------------------------------------------------------
__global__ void k_norm(const float* __restrict__ th,
                       unsigned short* __restrict__ thb,
                       unsigned short* __restrict__ thbT) {
    int p = blockIdx.x;       // 0..127
    int d = threadIdx.x;      // 0..127
    float v = 0.f;
    if (p < P_) v = th[p * D_ + d];
    float s = v * v;
    #pragma unroll
    for (int o = 32; o > 0; o >>= 1) s += __shfl_down(s, o, 64);
    __shared__ float red[2];
    if ((d & 63) == 0) red[d >> 6] = s;
    __syncthreads();
    float norm = fmaxf(sqrtf(red[0] + red[1]), 1e-12f);
    unsigned short r = f2b(v / norm);       // p>=100 -> 0/1e-12 = +0
    if (p < PPAD) thb[p * D_ + d] = r;
    thbT[d * KPAD + p] = r;
}

// ---------------------------------------------------------------------------
// Kernel 2: projections via bf16 MFMA 16x16x32 (unchanged — proven).
// ---------------------------------------------------------------------------
__global__ __launch_bounds__(256) void k_proj(
    const float* __restrict__ x, const float* __restrict__ y,
    const unsigned short* __restrict__ thb,
    unsigned short* __restrict__ xp, unsigned short* __restrict__ yp) {
    __shared__ unsigned short smem[32640];    // 65,280 B
    unsigned short* th_s = smem;              // [112][136]
    unsigned short* xs   = smem + 15232;      // [64][136]
    unsigned short* ys   = xs + 8704;         // [64][136]
    unsigned short* bufx = xs;                // [112][72] (alias, phase 2)
    unsigned short* bufy = bufx + 8064;       // [112][72]
    const int tid  = threadIdx.x;
    const int w    = tid >> 6;                // wave 0..3 -> rows w*16..+15
    const int lane = tid & 63;
    const int n    = lane & 15;
    const int quad = lane >> 4;
    const int row0 = blockIdx.x * 64;

    for (int g = tid; g < 1792; g += 256) {   // theta 112x128 bf16
        int r = g >> 4, c = (g & 15) << 3;
        *(uint4*)(th_s + r * 136 + c) = *(const uint4*)(thb + r * D_ + c);
    }
    for (int g = tid; g < 2048; g += 256) {   // x,y 64x128 fp32 -> bf16
        int r = g >> 5, c = (g & 31) << 2;
        float4 vx = *(const float4*)(x + (size_t)(row0 + r) * D_ + c);
        float4 vy = *(const float4*)(y + (size_t)(row0 + r) * D_ + c);
        *(ushort4*)(xs + r * 136 + c) =
            make_ushort4(f2b(vx.x), f2b(vx.y), f2b(vx.z), f2b(vx.w));
        *(ushort4*)(ys + r * 136 + c) =
            make_ushort4(f2b(vy.x), f2b(vy.y), f2b(vy.z), f2b(vy.w));
    }
    __syncthreads();

    short8 bx[4], by[4];
    #pragma unroll
    for (int ks = 0; ks < 4; ++ks) {
        bx[ks] = *(const short8*)(xs + (w * 16 + n) * 136 + ks * 32 + quad * 8);
        by[ks] = *(const short8*)(ys + (w * 16 + n) * 136 + ks * 32 + quad * 8);
    }
    __syncthreads();                          // xs/ys dead -> buf aliases ok

    #pragma unroll
    for (int pt = 0; pt < 7; ++pt) {
        floatx4 accx = {0.f, 0.f, 0.f, 0.f};
        floatx4 accy = {0.f, 0.f, 0.f, 0.f};
        #pragma unroll
        for (int ks = 0; ks < 4; ++ks) {
            short8 a = *(const short8*)(th_s + (pt * 16 + n) * 136 + ks * 32 + quad * 8);
            accx = __builtin_amdgcn_mfma_f32_16x16x32_bf16(a, bx[ks], accx, 0, 0, 0);
            accy = __builtin_amdgcn_mfma_f32_16x16x32_bf16(a, by[ks], accy, 0, 0, 0);
        }
        #pragma unroll
        for (int reg = 0; reg < 4; ++reg) {
            int p = pt * 16 + quad * 4 + reg;
            bufx[p * 72 + w * 16 + n] = f2b(accx[reg]);
            bufy[p * 72 + w * 16 + n] = f2b(accy[reg]);
        }
    }
    __syncthreads();

    for (int g = tid; g < 896; g += 256) {
        int p = g >> 3, c = (g & 7) << 3;
        *(uint4*)(xp + (size_t)p * BN_ + row0 + c) = *(const uint4*)(bufx + p * 72 + c);
        *(uint4*)(yp + (size_t)p * BN_ + row0 + c) = *(const uint4*)(bufy + p * 72 + c);
    }
}

// ---------------------------------------------------------------------------
// Kernel 3: fused counting sort + rank + diff.  Packed histogram: y counts in
// low 16 bits (+1), x counts in high 16 (+0x10000); max count 16384 < 2^16 so
// fields never interact and the packed exclusive scan is field-independent
// (total = 0x4000_4000, no cross-field carry).  One zero pass, one count
// pass, ONE scan, and the returning atomic's own field IS the intra-bin idx.
//
// R1 fix: __launch_bounds__(1024, 4) (was (1024, 8)).  The 8-waves/EU demand
// capped the allocator at <=64 VGPRs while live state through the scan is
// ~40+ regs (yw/xw/jy/jx + addrs) -> massive scratch spill: rocprof showed
// VGPR_Count=32, WRITE_SIZE 87 MB vs 13.4 MB ideal (+76 MB spill writes),
// FETCH 49 MB vs 26 MB, VALUBusy 9.5%.  Cap 128 eliminates spill; occupancy
// drops to 1 block/CU (16 waves) which still saturates the LDS-atomic pipe
// (32 independent atomics of ILP per thread).
// ---------------------------------------------------------------------------
__device__ __forceinline__ int binof(float v) {
    int k = (int)((v + 8.0f) * 256.0f);
    return k < 0 ? 0 : (k > NBIN - 1 ? NBIN - 1 : k);
}

__device__ __forceinline__ void scan4(unsigned* hist, volatile unsigned* wsum, int t) {
    unsigned v[4], run = 0;
    #pragma unroll
    for (int i = 0; i < 4; ++i) { unsigned h = hist[t * 4 + i]; v[i] = run; run += h; }
    const int lane = t & 63, w = t >> 6;
    unsigned inc = run;
    #pragma unroll
    for (int off = 1; off < 64; off <<= 1) {
        unsigned nbr = __shfl_up(inc, off, 64);
        if (lane >= off) inc += nbr;
    }
    if (lane == 63) wsum[w] = inc;
    __syncthreads();
    if (t == 0) {
        unsigned r2 = 0;
        #pragma unroll
        for (int i = 0; i < 16; ++i) { unsigned h = wsum[i]; wsum[i] = r2; r2 += h; }
    }
    __syncthreads();
    unsigned base = wsum[w] + (inc - run);
    #pragma unroll
    for (int i = 0; i < 4; ++i) hist[t * 4 + i] = base + v[i];
}

__global__ __launch_bounds__(1024, 4) void k_sortdiff(
    const unsigned short* __restrict__ xp, const unsigned short* __restrict__ yp,
    unsigned short* __restrict__ diff) {
    __shared__ unsigned hist[NBIN];           // 16 KB (packed y|x)
    __shared__ unsigned short ysort[N_];      // 32 KB
    __shared__ unsigned wsum[16];
    const size_t base = (size_t)blockIdx.x * N_ + (size_t)threadIdx.x * 16;
    const int t = threadIdx.x;

    // 16 contiguous elements per thread, uint4 loads (coalesced 2KB/wave)
    unsigned yw[8], xw[8];
    {
        uint4 a = *(const uint4*)(yp + base), b = *(const uint4*)(yp + base + 8);
        yw[0]=a.x; yw[1]=a.y; yw[2]=a.z; yw[3]=a.w;
        yw[4]=b.x; yw[5]=b.y; yw[6]=b.z; yw[7]=b.w;
        uint4 c = *(const uint4*)(xp + base), d = *(const uint4*)(xp + base + 8);
        xw[0]=c.x; xw[1]=c.y; xw[2]=c.z; xw[3]=c.w;
        xw[4]=d.x; xw[5]=d.y; xw[6]=d.z; xw[7]=d.w;
    }

    #pragma unroll
    for (int i = 0; i < 4; ++i) hist[t + i * 1024] = 0;
    __syncthreads();

    // ---- single packed count pass (returning: ret field IS intra-bin idx) ----
    unsigned jy[8], jx[8];
    #pragma unroll
    for (int k = 0; k < 8; ++k) {
        unsigned j0 = atomicAdd(&hist[binof(b2f((unsigned short)(yw[k] & 0xffff)))], 1u);
        unsigned j1 = atomicAdd(&hist[binof(b2f((unsigned short)(yw[k] >> 16)))], 1u);
        jy[k] = (j0 & 0xffffu) | (j1 << 16);
        unsigned i0 = atomicAdd(&hist[binof(b2f((unsigned short)(xw[k] & 0xffff)))], 0x10000u);
        unsigned i1 = atomicAdd(&hist[binof(b2f((unsigned short)(xw[k] >> 16)))], 0x10000u);
        jx[k] = (i0 >> 16) | (i1 & 0xffff0000u);
    }
    __syncthreads();
    scan4(hist, wsum, t);                     // packed exclusive prefix, both fields
    __syncthreads();

    // scatter y into LDS (low field) and fold x rank into jx (high field)
    #pragma unroll
    for (int k = 0; k < 8; ++k) {
        unsigned short e0 = (unsigned short)(yw[k] & 0xffff);
        unsigned short e1 = (unsigned short)(yw[k] >> 16);
        ysort[(hist[binof(b2f(e0))] & 0xffffu) + (jy[k] & 0xffffu)] = e0;
        ysort[(hist[binof(b2f(e1))] & 0xffffu) + (jy[k] >> 16)]     = e1;
        unsigned r0 = (hist[binof(b2f((unsigned short)(xw[k] & 0xffff)))] >> 16) + (jx[k] & 0xffffu);
        unsigned r1 = (hist[binof(b2f((unsigned short)(xw[k] >> 16)))] >> 16) + (jx[k] >> 16);
        jx[k] = r0 | (r1 << 16);
    }
    __syncthreads();

    // gather transported y, write diff
    unsigned ow[8];
    #pragma unroll
    for (int k = 0; k < 8; ++k) {
        float x0 = b2f((unsigned short)(xw[k] & 0xffff));
        float x1 = b2f((unsigned short)(xw[k] >> 16));
        unsigned short d0 = f2b(b2f(ysort[jx[k] & 0xffffu]) - x0);
        unsigned short d1 = f2b(b2f(ysort[jx[k] >> 16]) - x1);
        ow[k] = (unsigned)d0 | ((unsigned)d1 << 16);
    }
    *(uint4*)(diff + base)     = make_uint4(ow[0], ow[1], ow[2], ow[3]);
    *(uint4*)(diff + base + 8) = make_uint4(ow[4], ow[5], ow[6], ow[7]);
}

// ---------------------------------------------------------------------------
// Kernel 4: combine via bf16 MFMA, transpose fused into the LDS stage.
// Per block: stage diff[p][row0..row0+64] for p=0..99 (100 coalesced 128 B
// segments) pair-packed into Lp[k2][row] (dword = {k even lo16, k odd hi16});
// k2 rows 50..63 zeroed = NaN-safe K-pad.  A-frags: 4x ds_read_b32 per ks at
// (k2)*68 + r dwords — lanes map to bank (16*quad + n16) mod 32 = exact 2-way
// aliasing = free (m136).  B = thbT staged in LDS [128][136] (proven).
// C[m=row][n=d]; out = x + C/P.  LDS 52,224 B -> 3 blocks/CU, 12 waves/CU.
// ---------------------------------------------------------------------------
__global__ __launch_bounds__(256) void k_comb(
    const float* __restrict__ x, const unsigned short* __restrict__ diff,
    const unsigned short* __restrict__ thbT, float* __restrict__ out) {
    __shared__ unsigned short ths[128 * 136]; // 34,816 B
    __shared__ unsigned Lp[64 * 68];          // 17,408 B  [k2][row] pair-packed
    const int tid  = threadIdx.x;
    const int w    = tid >> 6;                // wave -> rows w*16..+15
    const int lane = tid & 63;
    const int n16  = lane & 15;
    const int quad = lane >> 4;
    const int row0 = blockIdx.x * 64;

    for (int g = tid; g < 2048; g += 256) {   // thbT 128x128 bf16 -> LDS
        int r = g >> 4, c = (g & 15) << 3;
        *(uint4*)(ths + r * 136 + c) = *(const uint4*)(thbT + r * KPAD + c);
    }
    for (int g = tid; g < 952; g += 256) Lp[50 * 68 + g] = 0;   // k2=50..63 pad
    for (int g = tid; g < 400; g += 256) {    // 50 p-pairs x 8 row-groups
        int p2 = g >> 3, rg = (g & 7) << 3;
        uint4 a = *(const uint4*)(diff + (size_t)(2 * p2) * BN_ + row0 + rg);
        uint4 b = *(const uint4*)(diff + (size_t)(2 * p2 + 1) * BN_ + row0 + rg);
        unsigned* dst = Lp + p2 * 68 + rg;
        dst[0] = (a.x & 0xffffu) | (b.x << 16);
        dst[1] = (a.x >> 16)     | (b.x & 0xffff0000u);
        dst[2] = (a.y & 0xffffu) | (b.y << 16);
        dst[3] = (a.y >> 16)     | (b.y & 0xffff0000u);
        dst[4] = (a.z & 0xffffu) | (b.z << 16);
        dst[5] = (a.z >> 16)     | (b.z & 0xffff0000u);
        dst[6] = (a.w & 0xffffu) | (b.w << 16);
        dst[7] = (a.w >> 16)     | (b.w & 0xffff0000u);
    }
    __syncthreads();

    // A-frags: lane row r = w*16+n16, k = ks*32 + quad*8 + 0..7
    const int r = w * 16 + n16;
    short8 af[4];
    #pragma unroll
    for (int ks = 0; ks < 4; ++ks) {
        union { unsigned u[4]; short8 v; } tu;
        #pragma unroll
        for (int m = 0; m < 4; ++m)
            tu.u[m] = Lp[(ks * 16 + quad * 4 + m) * 68 + r];
        af[ks] = tu.v;
    }

    floatx4 acc[8];
    #pragma unroll
    for (int nt = 0; nt < 8; ++nt) {
        acc[nt] = (floatx4){0.f, 0.f, 0.f, 0.f};
        #pragma unroll
        for (int ks = 0; ks < 4; ++ks) {
            short8 b = *(const short8*)(ths + (nt * 16 + n16) * 136 + ks * 32 + quad * 8);
            acc[nt] = __builtin_amdgcn_mfma_f32_16x16x32_bf16(af[ks], b, acc[nt], 0, 0, 0);
        }
    }

    const float invP = 1.0f / (float)P_;
    const size_t rbase = (size_t)(row0 + w * 16 + quad * 4) * D_ + n16;
    #pragma unroll
    for (int nt = 0; nt < 8; ++nt)
        #pragma unroll
        for (int reg = 0; reg < 4; ++reg) {
            size_t o = rbase + (size_t)reg * D_ + nt * 16;
            out[o] = fmaf(acc[nt][reg], invP, x[o]);
        }
}

// ---------------------------------------------------------------------------
// Workspace (bytes): thb[0, 32KB) thbT[32KB, 64KB) xp[64KB, +13.1MB)
// yp(+13.1MB) => ~26.3 MB. diff overwrites xp in place.
// ---------------------------------------------------------------------------
extern "C" void kernel_launch(void* const* d_in, const int* in_sizes, int n_in,
                              void* d_out, int out_size, void* d_ws, size_t ws_size,
                              hipStream_t stream) {
    const float* x  = (const float*)d_in[0];
    const float* y  = (const float*)d_in[1];
    const float* th = (const float*)d_in[2];
    float* out = (float*)d_out;
    char*  wsb = (char*)d_ws;

    unsigned short* thb  = (unsigned short*)wsb;
    unsigned short* thbT = (unsigned short*)(wsb + 32768);
    unsigned short* xpb  = (unsigned short*)(wsb + 65536);
    unsigned short* ypb  = xpb + PBN_;

    k_norm<<<128, 128, 0, stream>>>(th, thb, thbT);
    k_proj<<<BN_ / 64, 256, 0, stream>>>(x, y, thb, xpb, ypb);
    k_sortdiff<<<P_ * B_, 1024, 0, stream>>>(xpb, ypb, xpb);
    k_comb<<<BN_ / 64, 256, 0, stream>>>(x, xpb, thbT, out);
}